// Round 11
// baseline (204.042 us; speedup 1.0000x reference)
//
#include <hip/hip_runtime.h>
#include <math.h>

#define Hd 256
#define Wd 256
#define Cd 128
#define BIGV 1.0e9f
#define PLN 65536

typedef float f32x4 __attribute__((ext_vector_type(4)));
typedef __attribute__((address_space(1))) const float glb1;
typedef __attribute__((address_space(3))) float lds3;

static __device__ __forceinline__ float softplus_f(float x) {
    return fmaxf(x, 0.0f) + log1pf(expf(-fabsf(x)));
}

// ---- DPP helpers ----
#define FMAXBITS 0x7F7FFFFF
template<int CTRL, int RM>
static __device__ __forceinline__ float dpp_mv(float x) {
    return __int_as_float(__builtin_amdgcn_update_dpp(
        FMAXBITS, __float_as_int(x), CTRL, RM, 0xF, false));
}
template<int CTRL, int RM>
static __device__ __forceinline__ float dpp_min(float x) {
    return fminf(x, dpp_mv<CTRL, RM>(x));
}
static __device__ __forceinline__ float wave_prefmin(float x) {
    x = dpp_min<0x111, 0xF>(x);
    x = dpp_min<0x112, 0xF>(x);
    x = dpp_min<0x114, 0xF>(x);
    x = dpp_min<0x118, 0xF>(x);
    x = dpp_min<0x142, 0xA>(x);
    x = dpp_min<0x143, 0xC>(x);
    return x;
}

#define TILE 16
#define HPX 18
#define PXN 324
#define SP  325
#define CHUNK 32
#define CHF 16

// ---------------------------------------------------------------------------
// Kernel 1 (R22): cost partials at NS=4. 1024 blocks (tile, grp of 32 ch),
// 16-ch staged chunks (LDS 20.8KB) -> 4 blocks/CU (R9 had 2). Writes 9
// partial planes per group (norm + 8 dots).
// ---------------------------------------------------------------------------
__global__ __launch_bounds__(256) void k_costp(
    const float* __restrict__ feat, float* __restrict__ pcost)
{
    __shared__ float stage[CHF * SP];

    const int t    = threadIdx.x;
    const int tile = blockIdx.x & 255;
    const int grp  = blockIdx.x >> 8;          // 32-ch group
    const int chB  = grp << 5;
    const int r0   = (tile >> 4) * TILE;
    const int c0   = (tile & 15) * TILE;

    const int lr = t >> 4, lc = t & 15;
    const int r = r0 + lr, c = c0 + lc;
    const int px0 = (lr + 1) * HPX + (lc + 1);

    float dotv[8];
#pragma unroll
    for (int j = 0; j < 8; ++j) dotv[j] = 0.0f;
    float nrm_acc = 0.0f;

    for (int cc = 0; cc < 2; ++cc) {
        const int ch0 = chB + (cc << 4);
        __syncthreads();
        for (int i = t; i < PXN * 4; i += 256) {
            int pxi = i >> 2, f4 = i & 3;
            int pr = pxi / HPX;
            int pc = pxi - pr * HPX;
            int gr = r0 - 1 + pr, gc = c0 - 1 + pc;
            float4 v = make_float4(0.f, 0.f, 0.f, 0.f);
            if ((unsigned)gr < Hd && (unsigned)gc < Wd) {
                v = *reinterpret_cast<const float4*>(
                        &feat[(((gr << 8) + gc) * Cd) + ch0 + (f4 << 2)]);
            }
            int chb = f4 << 2;
            stage[(chb + 0) * SP + pxi] = v.x;
            stage[(chb + 1) * SP + pxi] = v.y;
            stage[(chb + 2) * SP + pxi] = v.z;
            stage[(chb + 3) * SP + pxi] = v.w;
        }
        __syncthreads();
        for (int ch = 0; ch < CHF; ++ch) {
            const float* pl = stage + ch * SP + px0;
            float x  = pl[0];
            float n0 = pl[-HPX - 1], n1 = pl[-HPX], n2 = pl[-HPX + 1];
            float n3 = pl[-1],                      n4 = pl[1];
            float n5 = pl[HPX - 1],  n6 = pl[HPX],  n7 = pl[HPX + 1];
            nrm_acc = fmaf(x, x, nrm_acc);
            dotv[0] = fmaf(x, n0, dotv[0]);
            dotv[1] = fmaf(x, n1, dotv[1]);
            dotv[2] = fmaf(x, n2, dotv[2]);
            dotv[3] = fmaf(x, n3, dotv[3]);
            dotv[4] = fmaf(x, n4, dotv[4]);
            dotv[5] = fmaf(x, n5, dotv[5]);
            dotv[6] = fmaf(x, n6, dotv[6]);
            dotv[7] = fmaf(x, n7, dotv[7]);
        }
    }

    const int p = (r << 8) + c;
    float* __restrict__ pb = pcost + (size_t)grp * 9 * PLN;
    pb[p] = nrm_acc;
#pragma unroll
    for (int j = 0; j < 8; ++j) pb[(1 + j) * PLN + p] = dotv[j];
}

// ---------------------------------------------------------------------------
// Kernel 2 (R20-proven, 4-group sums): cost FINISH + per-row prefix scans.
// ---------------------------------------------------------------------------
__global__ __launch_bounds__(256) void k_scan(
    const float* __restrict__ pcost, float* __restrict__ costP,
    float* __restrict__ PR, float* __restrict__ PRm,
    float* __restrict__ out)
{
    __shared__ float nrm[3 * 256];
    __shared__ float cE[256], cW[256];

    const int t = threadIdx.x;
    const int r = blockIdx.x;

    for (int i = t; i < 3 * 256; i += 256) {
        int rr = r - 1 + (i >> 8);
        int pc = i & 255;
        float s = 0.0f;
        if ((unsigned)rr < Hd)
#pragma unroll
            for (int g = 0; g < 4; ++g)
                s += pcost[(size_t)g * 9 * PLN + (rr << 8) + pc];
        nrm[i] = fmaxf(sqrtf(s), 1e-12f);
    }
    __syncthreads();

    const int p = (r << 8) + t;
    const float npv = nrm[256 + t];
    const int drr[8] = {-1,-1,-1, 0, 0, 1, 1, 1};
    const int dcc[8] = {-1, 0, 1,-1, 1,-1, 0, 1};
#pragma unroll
    for (int j = 0; j < 8; ++j) {
        int nr = r + drr[j], nc = t + dcc[j];
        float cj;
        if ((unsigned)nr < Hd && (unsigned)nc < Wd) {
            float dot = 0.0f;
#pragma unroll
            for (int g = 0; g < 4; ++g)
                dot += pcost[(size_t)g * 9 * PLN + (1 + j) * PLN + p];
            float nn = nrm[((drr[j] + 1) << 8) + nc];
            cj = 1.0f - dot / (npv * nn);
        } else {
            cj = BIGV;
        }
        costP[(j << 16) + p] = cj;
        out[p * 10 + 1 + j]  = cj;
        if (j == 4) cE[t] = cj;
        if (j == 3) cW[t] = cj;
    }
    __syncthreads();

    if (t < 64) {
        const int l = t;
        const int base = (r << 8) + (l << 2);
        {
            float a0 = cE[(l << 2) + 0];
            float a1 = a0 + cE[(l << 2) + 1];
            float a2 = a1 + cE[(l << 2) + 2];
            float a3 = a2 + cE[(l << 2) + 3];
            float ta = a3;
#pragma unroll
            for (int o = 1; o < 64; o <<= 1) {
                float xa = __shfl_up(ta, o, 64);
                if (l >= o) ta += xa;
            }
            float ea = __shfl_up(ta, 1, 64); if (l == 0) ea = 0.0f;
            float4 P; P.x = ea; P.y = ea + a0; P.z = ea + a1; P.w = ea + a2;
            *(float4*)&PR[base] = P;
        }
        {
            float w0 = cW[255 - (l << 2)];
            float w1_ = cW[254 - (l << 2)];
            float w2_ = cW[253 - (l << 2)];
            float w3 = cW[252 - (l << 2)];
            float a0 = w0, a1 = a0 + w1_, a2 = a1 + w2_, a3 = a2 + w3;
            float ta = a3;
#pragma unroll
            for (int o = 1; o < 64; o <<= 1) {
                float xa = __shfl_up(ta, o, 64);
                if (l >= o) ta += xa;
            }
            float ea = __shfl_up(ta, 1, 64); if (l == 0) ea = 0.0f;
            float4 P; P.x = ea; P.y = ea + a0; P.z = ea + a1; P.w = ea + a2;
            *(float4*)&PRm[base] = P;
        }
    }
}

// ---------------------------------------------------------------------------
// R22 sweep core: two-level pipeline. global_load_lds prefetches 12 rows
// ahead into 4 x 16KB LDS slots (counted vmcnt, never drained in-loop);
// ds_read_b128 pulls the current 4-row superblock to registers (lgkmcnt
// 12/8/4/0 + sched_barrier per rule #18). Covers the ~1600-cyc cross-XCD
// dirty-line latency that capped the DEPTH-4 register pipeline at 47.5us.
// vmcnt accounting (issue order: [16 glds batch]..[ds_reads][batch s+3]
// [4 stores]): peel 32/36/40, steady 44. VGPR ~= R5 core (16 f32x4 live).
// ---------------------------------------------------------------------------
template<int VD> static __device__ __forceinline__ int row_of(int ii) {
    int c = ii > 255 ? 255 : ii;
    return VD ? c : 255 - c;
}
template<int VD> static __device__ __forceinline__ int rowp_of(int ii) {
    int c = ii - 1; c = c < 0 ? 0 : (c > 255 ? 255 : c);
    return VD ? c : 255 - c;
}

template<int M, int VD>
static __device__ __forceinline__ void sweep_lds(
    int l, int sr, int sc,
    const float* __restrict__ PRu,
    const float* __restrict__ cInP,
    const float* __restrict__ cStP,
    const float* __restrict__ cDeP,
    float* __restrict__ O, float* ldsb)
{
    const int lane4 = l << 2;
    f32x4 sv = {BIGV, BIGV, BIGV, BIGV};
    {
        int kk = sc - lane4;
        if (kk == 0) sv[0] = 0.0f;
        if (kk == 1) sv[1] = 0.0f;
        if (kk == 2) sv[2] = 0.0f;
        if (kk == 3) sv[3] = 0.0f;
    }
    const int iStart = VD ? sr : 255 - sr;
    f32x4 Dp = {BIGV, BIGV, BIGV, BIGV};

#define KXc(v) (M ? (v)[3] : (v)[0])
#define KYc(v) (M ? (v)[2] : (v)[1])
#define KZc(v) (M ? (v)[1] : (v)[2])
#define KWc(v) (M ? (v)[0] : (v)[3])

    // float-index of plane-row (pl) of row rw of slot sl (256 floats each)
#define SLOTF(sl, rw, pl) ((((((sl) << 2) + (rw)) << 2) + (pl)) << 8)

#define GLD_ROW(sb, rw) do {                                                  \
        int j_ = ((sb) << 2) + (rw);                                          \
        int rP_ = row_of<VD>(j_), rC_ = rowp_of<VD>(j_);                      \
        int cO_ = M ? ((rC_ << 8) + 252 - lane4) : ((rC_ << 8) + lane4);      \
        int sl_ = (sb) & 3;                                                   \
        __builtin_amdgcn_global_load_lds((glb1*)(PRu + (rP_ << 8) + lane4),   \
            (lds3*)&ldsb[SLOTF(sl_, (rw), 0)], 16, 0, 0);                     \
        __builtin_amdgcn_global_load_lds((glb1*)(cInP + cO_),                 \
            (lds3*)&ldsb[SLOTF(sl_, (rw), 1)], 16, 0, 0);                     \
        __builtin_amdgcn_global_load_lds((glb1*)(cStP + cO_),                 \
            (lds3*)&ldsb[SLOTF(sl_, (rw), 2)], 16, 0, 0);                     \
        __builtin_amdgcn_global_load_lds((glb1*)(cDeP + cO_),                 \
            (lds3*)&ldsb[SLOTF(sl_, (rw), 3)], 16, 0, 0);                     \
    } while (0)

#define GLD_BATCH(sb) do {                                                    \
        GLD_ROW(sb, 0); GLD_ROW(sb, 1); GLD_ROW(sb, 2); GLD_ROW(sb, 3);       \
        __builtin_amdgcn_sched_barrier(0);                                    \
    } while (0)

#define ROW(sb, rw, LN) do {                                                  \
        asm volatile("s_waitcnt lgkmcnt(" #LN ")");                           \
        __builtin_amdgcn_sched_barrier(0);                                    \
        const int i__ = ((sb) << 2) + (rw);                                   \
        const int r__ = VD ? i__ : 255 - i__;                                 \
        f32x4 PRc = dPR[rw];                                                  \
        float tS0 = Dp[0] + KXc(dS[rw]), tS1 = Dp[1] + KYc(dS[rw]);           \
        float tS2 = Dp[2] + KZc(dS[rw]), tS3 = Dp[3] + KWc(dS[rw]);           \
        float tI0 = Dp[0] + KXc(dI[rw]), tI1 = Dp[1] + KYc(dI[rw]);           \
        float tI2 = Dp[2] + KZc(dI[rw]), tI3 = Dp[3] + KWc(dI[rw]);           \
        float tD0 = Dp[0] + KXc(dD[rw]), tD1 = Dp[1] + KYc(dD[rw]);           \
        float tD2 = Dp[2] + KZc(dD[rw]), tD3 = Dp[3] + KWc(dD[rw]);           \
        float tIm = dpp_mv<0x138, 0xF>(tI3);                                  \
        float tDn = dpp_mv<0x130, 0xF>(tD0);                                  \
        f32x4 cand;                                                           \
        cand[0] = fminf(tS0, fminf(tIm, tD1));                                \
        cand[1] = fminf(tS1, fminf(tI0, tD2));                                \
        cand[2] = fminf(tS2, fminf(tI1, tD3));                                \
        cand[3] = fminf(tS3, fminf(tI2, tDn));                                \
        if (i__ == iStart) {                                                  \
            cand[0] = fminf(cand[0], sv[0]); cand[1] = fminf(cand[1], sv[1]); \
            cand[2] = fminf(cand[2], sv[2]); cand[3] = fminf(cand[3], sv[3]); \
        }                                                                     \
        float z0 = cand[0] - PRc[0];                                          \
        float z1 = fminf(cand[1] - PRc[1], z0);                               \
        float z2 = fminf(cand[2] - PRc[2], z1);                               \
        float z3 = fminf(cand[3] - PRc[3], z2);                               \
        float w__ = wave_prefmin(z3);                                         \
        float e__ = dpp_mv<0x138, 0xF>(w__);                                  \
        f32x4 D__;                                                            \
        D__[0] = PRc[0] + fminf(z0, e__);                                     \
        D__[1] = PRc[1] + fminf(z1, e__);                                     \
        D__[2] = PRc[2] + fminf(z2, e__);                                     \
        D__[3] = PRc[3] + fminf(z3, e__);                                     \
        int voffO_ = ((r__ << 8) + lane4) << 2;                               \
        asm volatile("global_store_dwordx4 %0, %1, %2"                        \
                     :: "v"(voffO_), "v"(D__), "s"(O));                       \
        Dp = D__;                                                             \
    } while (0)

#define SBLOCK(sb, WN) do {                                                   \
        asm volatile("s_waitcnt vmcnt(" #WN ")");                             \
        __builtin_amdgcn_sched_barrier(0);                                    \
        const int sl_ = (sb) & 3;                                             \
        f32x4 dPR[4], dI[4], dS[4], dD[4];                                    \
        {                                                                     \
            int a0_ = (SLOTF(sl_, 0, 0) + lane4) << 2;                        \
            asm volatile("ds_read_b128 %0, %1"              : "=v"(dPR[0]) : "v"(a0_)); \
            asm volatile("ds_read_b128 %0, %1 offset:1024"  : "=v"(dI[0])  : "v"(a0_)); \
            asm volatile("ds_read_b128 %0, %1 offset:2048"  : "=v"(dS[0])  : "v"(a0_)); \
            asm volatile("ds_read_b128 %0, %1 offset:3072"  : "=v"(dD[0])  : "v"(a0_)); \
            int a1_ = (SLOTF(sl_, 1, 0) + lane4) << 2;                        \
            asm volatile("ds_read_b128 %0, %1"              : "=v"(dPR[1]) : "v"(a1_)); \
            asm volatile("ds_read_b128 %0, %1 offset:1024"  : "=v"(dI[1])  : "v"(a1_)); \
            asm volatile("ds_read_b128 %0, %1 offset:2048"  : "=v"(dS[1])  : "v"(a1_)); \
            asm volatile("ds_read_b128 %0, %1 offset:3072"  : "=v"(dD[1])  : "v"(a1_)); \
            int a2_ = (SLOTF(sl_, 2, 0) + lane4) << 2;                        \
            asm volatile("ds_read_b128 %0, %1"              : "=v"(dPR[2]) : "v"(a2_)); \
            asm volatile("ds_read_b128 %0, %1 offset:1024"  : "=v"(dI[2])  : "v"(a2_)); \
            asm volatile("ds_read_b128 %0, %1 offset:2048"  : "=v"(dS[2])  : "v"(a2_)); \
            asm volatile("ds_read_b128 %0, %1 offset:3072"  : "=v"(dD[2])  : "v"(a2_)); \
            int a3_ = (SLOTF(sl_, 3, 0) + lane4) << 2;                        \
            asm volatile("ds_read_b128 %0, %1"              : "=v"(dPR[3]) : "v"(a3_)); \
            asm volatile("ds_read_b128 %0, %1 offset:1024"  : "=v"(dI[3])  : "v"(a3_)); \
            asm volatile("ds_read_b128 %0, %1 offset:2048"  : "=v"(dS[3])  : "v"(a3_)); \
            asm volatile("ds_read_b128 %0, %1 offset:3072"  : "=v"(dD[3])  : "v"(a3_)); \
        }                                                                     \
        __builtin_amdgcn_sched_barrier(0);                                    \
        GLD_BATCH((sb) + 3);                                                  \
        ROW(sb, 0, 12); ROW(sb, 1, 8); ROW(sb, 2, 4); ROW(sb, 3, 0);          \
    } while (0)

    GLD_BATCH(0); GLD_BATCH(1); GLD_BATCH(2);
    SBLOCK(0, 32);
    SBLOCK(1, 36);
    SBLOCK(2, 40);
    for (int sb = 3; sb < 64; ++sb) { SBLOCK(sb, 44); }
    asm volatile("s_waitcnt vmcnt(0)");

#undef SBLOCK
#undef ROW
#undef GLD_BATCH
#undef GLD_ROW
#undef SLOTF
#undef KXc
#undef KYc
#undef KZc
#undef KWc
}

// ---------------------------------------------------------------------------
// Kernel 3 (R22): blocks 0..3 = LDS-pipelined sweeps (64KB LDS); blocks
// 4..4+256*nsh = heuristic partial blocks (nsh=4: 32ch each, nsh=2: R8-exact
// 64ch halves). Shared-LDS union (single smemF) so LDS stays 64KB.
// ---------------------------------------------------------------------------
__global__ __launch_bounds__(256) void k_main(
    const float* __restrict__ feat, const float* __restrict__ w1,
    const int* __restrict__ endn,
    const float* __restrict__ costP, const float* __restrict__ PR,
    const float* __restrict__ PRm, const int* __restrict__ startn,
    int nsh, float* __restrict__ distQ, float* __restrict__ part)
{
    __shared__ float smemF[16384];    // 64KB: sweep slots / heur staging

    if (blockIdx.x < 4) {
        const int l = threadIdx.x;
        if (l >= 64) return;
        __builtin_amdgcn_s_setprio(1);
        const int sw  = blockIdx.x;
        const int sr  = startn[0];
        const int sc0 = startn[1];
        float* O = distQ + (sw << 16);
        if (sw == 0)
            sweep_lds<0,1>(l, sr, sc0,       PR,  costP + (7<<16), costP + (6<<16), costP + (5<<16), O, smemF);
        else if (sw == 1)
            sweep_lds<1,1>(l, sr, 255 - sc0, PRm, costP + (5<<16), costP + (6<<16), costP + (7<<16), O, smemF);
        else if (sw == 2)
            sweep_lds<0,0>(l, sr, sc0,       PR,  costP + (2<<16), costP + (1<<16), costP + (0<<16), O, smemF);
        else
            sweep_lds<1,0>(l, sr, 255 - sc0, PRm, costP + (0<<16), costP + (1<<16), costP + (2<<16), O, smemF);
        return;
    }

    // ============== HEURISTIC PARTIAL BLOCK (chPer = 128/nsh channels) =====
    float*  stage = smemF;                         // 10400 floats
    float4* w1L   = (float4*)(smemF + 10400);      // up to 512 float4
    float*  endfL = smemF + 12448;                 // 64 floats

    const int t     = threadIdx.x;
    const int hb    = blockIdx.x - 4;
    const int tile  = hb & 255;
    const int grp   = hb >> 8;
    const int chPer = Cd / nsh;
    const int chB   = grp * chPer;
    const int r0    = (tile >> 4) * TILE;
    const int c0    = (tile & 15) * TILE;
    const bool isAbs = (chB < 64);                 // groups below ch64 do abs

    for (int i = t; i < chPer * 8; i += 256)
        w1L[i] = ((const float4*)w1)[(chB << 3) + i];
    const int er = endn[0], ec = endn[1];
    if (isAbs && t < chPer)
        endfL[t] = feat[(er * Wd + ec) * Cd + chB + t];

    const int lr = t >> 4, lc = t & 15;
    const int r = r0 + lr, c = c0 + lc;
    const int px0 = (lr + 1) * HPX + (lc + 1);

    float4 hv[8];
#pragma unroll
    for (int j = 0; j < 8; ++j) hv[j] = make_float4(0.f, 0.f, 0.f, 0.f);
    float gm_acc = 0.0f, va_acc = 0.0f;

    for (int cc = 0; cc < chPer / CHUNK; ++cc) {
        const int ch0 = chB + (cc << 5);
        __syncthreads();
        for (int i = t; i < PXN * 8; i += 256) {
            int pxi = i >> 3, f4 = i & 7;
            int pr = pxi / HPX;
            int pc = pxi - pr * HPX;
            int gr = r0 - 1 + pr, gc = c0 - 1 + pc;
            float4 v = make_float4(0.f, 0.f, 0.f, 0.f);
            if ((unsigned)gr < Hd && (unsigned)gc < Wd) {
                v = *reinterpret_cast<const float4*>(
                        &feat[(((gr << 8) + gc) * Cd) + ch0 + (f4 << 2)]);
            }
            int chb = f4 << 2;
            stage[(chb + 0) * SP + pxi] = v.x;
            stage[(chb + 1) * SP + pxi] = v.y;
            stage[(chb + 2) * SP + pxi] = v.z;
            stage[(chb + 3) * SP + pxi] = v.w;
        }
        __syncthreads();
        for (int ch = 0; ch < CHUNK; ++ch) {
            const float* pl = stage + ch * SP + px0;
            float x  = pl[0];
            float n0 = pl[-HPX - 1], n1 = pl[-HPX], n2 = pl[-HPX + 1];
            float n3 = pl[-1],                      n4 = pl[1];
            float n5 = pl[HPX - 1],  n6 = pl[HPX],  n7 = pl[HPX + 1];

            float gx = (n2 + 2.f * n4 + n7) - (n0 + 2.f * n3 + n5);
            float gy = (n5 + 2.f * n6 + n7) - (n0 + 2.f * n1 + n2);
            gm_acc += sqrtf(gx * gx + gy * gy);

            if (!isAbs) {
                float s1 = x + n0 + n1 + n2 + n3 + n4 + n5 + n6 + n7;
                float s2 = x*x + n0*n0 + n1*n1 + n2*n2 + n3*n3 + n4*n4
                         + n5*n5 + n6*n6 + n7*n7;
                float m = s1 * (1.0f / 9.0f);
                va_acc += s2 * (1.0f / 9.0f) - m * m;
            } else {
                float dlf = x - endfL[(cc << 5) + ch];
                va_acc = fmaf(dlf, dlf, va_acc);
            }

            const float4* __restrict__ wr4 = &w1L[((cc << 5) + ch) << 3];
#pragma unroll
            for (int j4 = 0; j4 < 8; ++j4) {
                float4 wv = wr4[j4];
                hv[j4].x = fmaf(x, wv.x, hv[j4].x);
                hv[j4].y = fmaf(x, wv.y, hv[j4].y);
                hv[j4].z = fmaf(x, wv.z, hv[j4].z);
                hv[j4].w = fmaf(x, wv.w, hv[j4].w);
            }
        }
    }

    const int p = (r << 8) + c;
    float* __restrict__ pb = part + (size_t)grp * 34 * PLN;
    pb[p]         = gm_acc;
    pb[PLN + p]   = va_acc;
#pragma unroll
    for (int j4 = 0; j4 < 8; ++j4) {
        pb[(2 + (j4 << 2) + 0) * PLN + p] = hv[j4].x;
        pb[(2 + (j4 << 2) + 1) * PLN + p] = hv[j4].y;
        pb[(2 + (j4 << 2) + 2) * PLN + p] = hv[j4].z;
        pb[(2 + (j4 << 2) + 3) * PLN + p] = hv[j4].w;
    }
}

// ---------------------------------------------------------------------------
// Kernel 4 (R22): merge dist planes + heuristic epilogue over nsh groups.
// ---------------------------------------------------------------------------
__global__ __launch_bounds__(256) void k_merge(
    const float* __restrict__ feat,
    const float* __restrict__ b1, const float* __restrict__ w2,
    const float* __restrict__ b2, const float* __restrict__ dlt,
    const float* __restrict__ gmm, const float* __restrict__ bta,
    const int* __restrict__ endn, int nsh,
    const float* __restrict__ distQ, const float* __restrict__ part,
    float* __restrict__ out)
{
    __shared__ float vendL[64];
    __shared__ float vendS_;

    const int t = threadIdx.x;
    const int p = blockIdx.x * 256 + t;

    const int er = endn[0], ec = endn[1];
    if (t < 64) {
        float s1 = 0.0f, s2 = 0.0f;
#pragma unroll
        for (int dr = -1; dr <= 1; ++dr)
#pragma unroll
            for (int dc = -1; dc <= 1; ++dc) {
                int gr = er + dr, gc = ec + dc;
                if ((unsigned)gr < Hd && (unsigned)gc < Wd) {
                    float x = feat[((gr << 8) + gc) * Cd + 64 + t];
                    s1 += x; s2 = fmaf(x, x, s2);
                }
            }
        float m = s1 * (1.0f / 9.0f);
        vendL[t] = s2 * (1.0f / 9.0f) - m * m;
    }
    __syncthreads();
    if (t < 64) {
        float v = vendL[t];
#pragma unroll
        for (int o = 32; o > 0; o >>= 1) v += __shfl_down(v, o, 64);
        if (t == 0) vendS_ = v;
    }
    __syncthreads();
    const float vend = vendS_;

    float gm = 0.0f, abs2 = 0.0f, var = 0.0f;
    for (int g = 0; g < nsh; ++g) {
        const float* __restrict__ pg = part + (size_t)g * 34 * PLN;
        gm += pg[p];
        float va = pg[PLN + p];
        if (g < (nsh >> 1)) abs2 += va; else var += va;
    }
    float o = b2[0];
    for (int j = 0; j < 32; ++j) {
        float hj = b1[j];
        for (int g = 0; g < nsh; ++g)
            hj += part[(size_t)g * 34 * PLN + (2 + j) * PLN + p];
        o = fmaf(fmaxf(hj, 0.0f), w2[j], o);
    }
    float omg = 1.0f / (1.0f + expf(-o));
    float dS = softplus_f(dlt[0]);
    float gS = softplus_f(gmm[0]);
    float bS = softplus_f(bta[0]);
    float heur = dS * (gm * (1.0f / 128.0f)) + omg * gS * (vend - var)
               + (1.0f - omg) * bS * sqrtf(abs2);
    out[p * 10] = fmaxf(heur, 0.0f);

    int pm = (p & ~255) + (255 - (p & 255));
    float v = fminf(fminf(distQ[p],              distQ[(2 << 16) + p]),
                    fminf(distQ[(1 << 16) + pm], distQ[(3 << 16) + pm]));
    out[p * 10 + 9] = fminf(v, BIGV);
}

// ---------------------------------------------------------------------------
extern "C" void kernel_launch(void* const* d_in, const int* in_sizes, int n_in,
                              void* d_out, int out_size, void* d_ws, size_t ws_size,
                              hipStream_t stream)
{
    const float* feat  = (const float*)d_in[0];
    const float* dlt   = (const float*)d_in[1];
    const float* gmm   = (const float*)d_in[2];
    const float* bta   = (const float*)d_in[3];
    const float* w1    = (const float*)d_in[4];
    const float* b1    = (const float*)d_in[5];
    const float* w2    = (const float*)d_in[6];
    const float* b2    = (const float*)d_in[7];
    const int*   startn= (const int*)d_in[8];
    const int*   endn  = (const int*)d_in[9];
    float* out = (float*)d_out;
    float* ws  = (float*)d_ws;

    float* costP = ws;                    // 8 planes
    float* PR    = ws + 8  * PLN;
    float* PRm   = ws + 9  * PLN;
    float* distQ = ws + 10 * PLN;         // 4 planes
    float* part  = ws + 14 * PLN;         // heur partials; pcost aliased here
    float* pcost = part;                  // 36 planes, dead before heur writes

    // heur split: nsh=4 needs 14 + 4*34 = 150 planes (39.3MB); else nsh=2
    // (82 planes, R9-proven footprint).
    const size_t need4 = (size_t)(14 + 4 * 34) * PLN * sizeof(float);
    const int nsh = (ws_size >= need4) ? 4 : 2;

    k_costp<<<1024, 256, 0, stream>>>(feat, pcost);
    k_scan<<<256, 256, 0, stream>>>(pcost, costP, PR, PRm, out);
    k_main<<<4 + 256 * nsh, 256, 0, stream>>>(feat, w1, endn,
                                              costP, PR, PRm, startn,
                                              nsh, distQ, part);
    k_merge<<<256, 256, 0, stream>>>(feat, b1, w2, b2, dlt, gmm, bta, endn,
                                     nsh, distQ, part, out);
}

// Round 12
// 163.624 us; speedup vs baseline: 1.2470x; 1.2470x over previous
//
#include <hip/hip_runtime.h>
#include <math.h>

#define Hd 256
#define Wd 256
#define Cd 128
#define BIGV 1.0e9f
#define PLN 65536

typedef float f32x4 __attribute__((ext_vector_type(4)));

static __device__ __forceinline__ float softplus_f(float x) {
    return fmaxf(x, 0.0f) + log1pf(expf(-fabsf(x)));
}

// ---- DPP helpers ----
#define FMAXBITS 0x7F7FFFFF
template<int CTRL, int RM>
static __device__ __forceinline__ float dpp_mv(float x) {
    return __int_as_float(__builtin_amdgcn_update_dpp(
        FMAXBITS, __float_as_int(x), CTRL, RM, 0xF, false));
}
template<int CTRL, int RM>
static __device__ __forceinline__ float dpp_min(float x) {
    return fminf(x, dpp_mv<CTRL, RM>(x));
}
static __device__ __forceinline__ float wave_prefmin(float x) {
    x = dpp_min<0x111, 0xF>(x);
    x = dpp_min<0x112, 0xF>(x);
    x = dpp_min<0x114, 0xF>(x);
    x = dpp_min<0x118, 0xF>(x);
    x = dpp_min<0x142, 0xA>(x);
    x = dpp_min<0x143, 0xC>(x);
    return x;
}

#define TILE 16
#define HPX 18
#define PXN 324
#define SP  325
#define CHUNK 32
#define CHF 16

// ---------------------------------------------------------------------------
// Kernel 1 (R11-proven): cost partials at NS=4. 1024 blocks (tile, 32-ch
// grp), 16-ch staged chunks (LDS 20.8KB -> ~8 blocks/CU). Writes 9 partial
// planes per group (norm + 8 dots).
// ---------------------------------------------------------------------------
__global__ __launch_bounds__(256) void k_costp(
    const float* __restrict__ feat, float* __restrict__ pcost)
{
    __shared__ float stage[CHF * SP];

    const int t    = threadIdx.x;
    const int tile = blockIdx.x & 255;
    const int grp  = blockIdx.x >> 8;
    const int chB  = grp << 5;
    const int r0   = (tile >> 4) * TILE;
    const int c0   = (tile & 15) * TILE;

    const int lr = t >> 4, lc = t & 15;
    const int r = r0 + lr, c = c0 + lc;
    const int px0 = (lr + 1) * HPX + (lc + 1);

    float dotv[8];
#pragma unroll
    for (int j = 0; j < 8; ++j) dotv[j] = 0.0f;
    float nrm_acc = 0.0f;

    for (int cc = 0; cc < 2; ++cc) {
        const int ch0 = chB + (cc << 4);
        __syncthreads();
        for (int i = t; i < PXN * 4; i += 256) {
            int pxi = i >> 2, f4 = i & 3;
            int pr = pxi / HPX;
            int pc = pxi - pr * HPX;
            int gr = r0 - 1 + pr, gc = c0 - 1 + pc;
            float4 v = make_float4(0.f, 0.f, 0.f, 0.f);
            if ((unsigned)gr < Hd && (unsigned)gc < Wd) {
                v = *reinterpret_cast<const float4*>(
                        &feat[(((gr << 8) + gc) * Cd) + ch0 + (f4 << 2)]);
            }
            int chb = f4 << 2;
            stage[(chb + 0) * SP + pxi] = v.x;
            stage[(chb + 1) * SP + pxi] = v.y;
            stage[(chb + 2) * SP + pxi] = v.z;
            stage[(chb + 3) * SP + pxi] = v.w;
        }
        __syncthreads();
        for (int ch = 0; ch < CHF; ++ch) {
            const float* pl = stage + ch * SP + px0;
            float x  = pl[0];
            float n0 = pl[-HPX - 1], n1 = pl[-HPX], n2 = pl[-HPX + 1];
            float n3 = pl[-1],                      n4 = pl[1];
            float n5 = pl[HPX - 1],  n6 = pl[HPX],  n7 = pl[HPX + 1];
            nrm_acc = fmaf(x, x, nrm_acc);
            dotv[0] = fmaf(x, n0, dotv[0]);
            dotv[1] = fmaf(x, n1, dotv[1]);
            dotv[2] = fmaf(x, n2, dotv[2]);
            dotv[3] = fmaf(x, n3, dotv[3]);
            dotv[4] = fmaf(x, n4, dotv[4]);
            dotv[5] = fmaf(x, n5, dotv[5]);
            dotv[6] = fmaf(x, n6, dotv[6]);
            dotv[7] = fmaf(x, n7, dotv[7]);
        }
    }

    const int p = (r << 8) + c;
    float* __restrict__ pb = pcost + (size_t)grp * 9 * PLN;
    pb[p] = nrm_acc;
#pragma unroll
    for (int j = 0; j < 8; ++j) pb[(1 + j) * PLN + p] = dotv[j];
}

// ---------------------------------------------------------------------------
// Kernel 2 (R11-proven): cost FINISH (4-group sums) + per-row prefix scans.
// ---------------------------------------------------------------------------
__global__ __launch_bounds__(256) void k_scan(
    const float* __restrict__ pcost, float* __restrict__ costP,
    float* __restrict__ PR, float* __restrict__ PRm,
    float* __restrict__ out)
{
    __shared__ float nrm[3 * 256];
    __shared__ float cE[256], cW[256];

    const int t = threadIdx.x;
    const int r = blockIdx.x;

    for (int i = t; i < 3 * 256; i += 256) {
        int rr = r - 1 + (i >> 8);
        int pc = i & 255;
        float s = 0.0f;
        if ((unsigned)rr < Hd)
#pragma unroll
            for (int g = 0; g < 4; ++g)
                s += pcost[(size_t)g * 9 * PLN + (rr << 8) + pc];
        nrm[i] = fmaxf(sqrtf(s), 1e-12f);
    }
    __syncthreads();

    const int p = (r << 8) + t;
    const float npv = nrm[256 + t];
    const int drr[8] = {-1,-1,-1, 0, 0, 1, 1, 1};
    const int dcc[8] = {-1, 0, 1,-1, 1,-1, 0, 1};
#pragma unroll
    for (int j = 0; j < 8; ++j) {
        int nr = r + drr[j], nc = t + dcc[j];
        float cj;
        if ((unsigned)nr < Hd && (unsigned)nc < Wd) {
            float dot = 0.0f;
#pragma unroll
            for (int g = 0; g < 4; ++g)
                dot += pcost[(size_t)g * 9 * PLN + (1 + j) * PLN + p];
            float nn = nrm[((drr[j] + 1) << 8) + nc];
            cj = 1.0f - dot / (npv * nn);
        } else {
            cj = BIGV;
        }
        costP[(j << 16) + p] = cj;
        out[p * 10 + 1 + j]  = cj;
        if (j == 4) cE[t] = cj;
        if (j == 3) cW[t] = cj;
    }
    __syncthreads();

    if (t < 64) {
        const int l = t;
        const int base = (r << 8) + (l << 2);
        {
            float a0 = cE[(l << 2) + 0];
            float a1 = a0 + cE[(l << 2) + 1];
            float a2 = a1 + cE[(l << 2) + 2];
            float a3 = a2 + cE[(l << 2) + 3];
            float ta = a3;
#pragma unroll
            for (int o = 1; o < 64; o <<= 1) {
                float xa = __shfl_up(ta, o, 64);
                if (l >= o) ta += xa;
            }
            float ea = __shfl_up(ta, 1, 64); if (l == 0) ea = 0.0f;
            float4 P; P.x = ea; P.y = ea + a0; P.z = ea + a1; P.w = ea + a2;
            *(float4*)&PR[base] = P;
        }
        {
            float w0 = cW[255 - (l << 2)];
            float w1_ = cW[254 - (l << 2)];
            float w2_ = cW[253 - (l << 2)];
            float w3 = cW[252 - (l << 2)];
            float a0 = w0, a1 = a0 + w1_, a2 = a1 + w2_, a3 = a2 + w3;
            float ta = a3;
#pragma unroll
            for (int o = 1; o < 64; o <<= 1) {
                float xa = __shfl_up(ta, o, 64);
                if (l >= o) ta += xa;
            }
            float ea = __shfl_up(ta, 1, 64); if (l == 0) ea = 0.0f;
            float4 P; P.x = ea; P.y = ea + a0; P.z = ea + a1; P.w = ea + a2;
            *(float4*)&PRm[base] = P;
        }
    }
}

// ---------------------------------------------------------------------------
// R5-EXACT sweep core (proven 47.5us standalone): volatile-asm pipelined,
// SDEPTH=4. R6: deeper register pipelines spill. R11: LDS-staged rebuild
// also loses (ds_read latency on the serial chain + LDS union starves the
// co-resident heuristic). This register core is the best known -- keep.
// ---------------------------------------------------------------------------
#define SDEPTH 4

template<int VD> static __device__ __forceinline__ int row_of(int ii) {
    int c = ii > 255 ? 255 : ii;
    return VD ? c : 255 - c;
}
template<int VD> static __device__ __forceinline__ int rowp_of(int ii) {
    int c = ii - 1; c = c < 0 ? 0 : (c > 255 ? 255 : c);
    return VD ? c : 255 - c;
}

template<int M, int VD>
static __device__ __forceinline__ void sweep_run(
    int l, int sr, int sc,
    const float* __restrict__ PRu,
    const float* __restrict__ cInP,
    const float* __restrict__ cStP,
    const float* __restrict__ cDeP,
    float* __restrict__ O)
{
    const int lane4 = l << 2;
    f32x4 sv = {BIGV, BIGV, BIGV, BIGV};
    {
        int kk = sc - lane4;
        if (kk == 0) sv[0] = 0.0f;
        if (kk == 1) sv[1] = 0.0f;
        if (kk == 2) sv[2] = 0.0f;
        if (kk == 3) sv[3] = 0.0f;
    }
    const int iStart = VD ? sr : 255 - sr;

    f32x4 bPR[SDEPTH], bI[SDEPTH], bS[SDEPTH], bD[SDEPTH];
    f32x4 Dp = {BIGV, BIGV, BIGV, BIGV};

#define KXc(v) (M ? (v)[3] : (v)[0])
#define KYc(v) (M ? (v)[2] : (v)[1])
#define KZc(v) (M ? (v)[1] : (v)[2])
#define KWc(v) (M ? (v)[0] : (v)[3])

#define SW_ISSUE(slot, jn) do {                                               \
        int rP_ = row_of<VD>(jn), rC_ = rowp_of<VD>(jn);                      \
        int voffP_ = ((rP_ << 8) + lane4) << 2;                               \
        int voffC_ = (M ? ((rC_ << 8) + 252 - lane4)                          \
                        : ((rC_ << 8) + lane4)) << 2;                         \
        asm volatile("global_load_dwordx4 %0, %1, %2"                         \
                     : "=v"(bPR[slot]) : "v"(voffP_), "s"(PRu));              \
        asm volatile("global_load_dwordx4 %0, %1, %2"                         \
                     : "=v"(bI[slot])  : "v"(voffC_), "s"(cInP));             \
        asm volatile("global_load_dwordx4 %0, %1, %2"                         \
                     : "=v"(bS[slot])  : "v"(voffC_), "s"(cStP));             \
        asm volatile("global_load_dwordx4 %0, %1, %2"                         \
                     : "=v"(bD[slot])  : "v"(voffC_), "s"(cDeP));             \
    } while (0)

#define SW_WAIT(n) do {                                                       \
        asm volatile("s_waitcnt vmcnt(" #n ")");                              \
        __builtin_amdgcn_sched_barrier(0);                                    \
    } while (0)

#define SW_BODY(slot, ivar) do {                                              \
        const int i__ = (ivar);                                               \
        const int r__ = VD ? i__ : 255 - i__;                                 \
        f32x4 PRc = bPR[slot];                                                \
        float tS0 = Dp[0] + KXc(bS[slot]), tS1 = Dp[1] + KYc(bS[slot]);       \
        float tS2 = Dp[2] + KZc(bS[slot]), tS3 = Dp[3] + KWc(bS[slot]);       \
        float tI0 = Dp[0] + KXc(bI[slot]), tI1 = Dp[1] + KYc(bI[slot]);       \
        float tI2 = Dp[2] + KZc(bI[slot]), tI3 = Dp[3] + KWc(bI[slot]);       \
        float tD0 = Dp[0] + KXc(bD[slot]), tD1 = Dp[1] + KYc(bD[slot]);       \
        float tD2 = Dp[2] + KZc(bD[slot]), tD3 = Dp[3] + KWc(bD[slot]);       \
        float tIm = dpp_mv<0x138, 0xF>(tI3);   /* wave_shr1 */                \
        float tDn = dpp_mv<0x130, 0xF>(tD0);   /* wave_shl1 */                \
        f32x4 cand;                                                           \
        cand[0] = fminf(tS0, fminf(tIm, tD1));                                \
        cand[1] = fminf(tS1, fminf(tI0, tD2));                                \
        cand[2] = fminf(tS2, fminf(tI1, tD3));                                \
        cand[3] = fminf(tS3, fminf(tI2, tDn));                                \
        if (i__ == iStart) {                                                  \
            cand[0] = fminf(cand[0], sv[0]); cand[1] = fminf(cand[1], sv[1]); \
            cand[2] = fminf(cand[2], sv[2]); cand[3] = fminf(cand[3], sv[3]); \
        }                                                                     \
        float z0 = cand[0] - PRc[0];                                          \
        float z1 = fminf(cand[1] - PRc[1], z0);                               \
        float z2 = fminf(cand[2] - PRc[2], z1);                               \
        float z3 = fminf(cand[3] - PRc[3], z2);                               \
        float w__ = wave_prefmin(z3);                                         \
        float e__ = dpp_mv<0x138, 0xF>(w__);   /* exclusive prefix */         \
        f32x4 D__;                                                            \
        D__[0] = PRc[0] + fminf(z0, e__);                                     \
        D__[1] = PRc[1] + fminf(z1, e__);                                     \
        D__[2] = PRc[2] + fminf(z2, e__);                                     \
        D__[3] = PRc[3] + fminf(z3, e__);                                     \
        int voffO_ = ((r__ << 8) + lane4) << 2;                               \
        asm volatile("global_store_dwordx4 %0, %1, %2"                        \
                     :: "v"(voffO_), "v"(D__), "s"(O));                       \
        Dp = D__;                                                             \
        SW_ISSUE(slot, i__ + SDEPTH);                                         \
    } while (0)

#pragma unroll
    for (int k = 0; k < SDEPTH; ++k) SW_ISSUE(k, k);

    SW_WAIT(12); SW_BODY(0, 0);
    SW_WAIT(13); SW_BODY(1, 1);
    SW_WAIT(14); SW_BODY(2, 2);
    SW_WAIT(15); SW_BODY(3, 3);
    for (int ib = SDEPTH; ib < 256; ib += SDEPTH) {
        SW_WAIT(15); SW_BODY(0, ib + 0);
        SW_WAIT(15); SW_BODY(1, ib + 1);
        SW_WAIT(15); SW_BODY(2, ib + 2);
        SW_WAIT(15); SW_BODY(3, ib + 3);
    }
    asm volatile("s_waitcnt vmcnt(0)");

#undef SW_ISSUE
#undef SW_WAIT
#undef SW_BODY
#undef KXc
#undef KYc
#undef KZc
#undef KWc
}

// ---------------------------------------------------------------------------
// Kernel 3 (R9 byte-exact, proven 52us): blocks 0..3 = sweeps; 4..515 =
// heuristic half-blocks (64ch, 49KB LDS -> 3 blocks/CU). R11 lesson: do NOT
// inflate this kernel's LDS for the sweep path.
// ---------------------------------------------------------------------------
__global__ __launch_bounds__(256) void k_main(
    const float* __restrict__ feat,
    const float* __restrict__ w1,
    const int* __restrict__ endn,
    const float* __restrict__ costP, const float* __restrict__ PR,
    const float* __restrict__ PRm, const int* __restrict__ startn,
    float* __restrict__ distQ, float* __restrict__ part)
{
    if (blockIdx.x < 4) {
        const int l = threadIdx.x;
        if (l >= 64) return;
        __builtin_amdgcn_s_setprio(1);
        const int sw  = blockIdx.x;
        const int sr  = startn[0];
        const int sc0 = startn[1];
        float* O = distQ + (sw << 16);
        if (sw == 0)
            sweep_run<0,1>(l, sr, sc0,       PR,  costP + (7<<16), costP + (6<<16), costP + (5<<16), O);
        else if (sw == 1)
            sweep_run<1,1>(l, sr, 255 - sc0, PRm, costP + (5<<16), costP + (6<<16), costP + (7<<16), O);
        else if (sw == 2)
            sweep_run<0,0>(l, sr, sc0,       PR,  costP + (2<<16), costP + (1<<16), costP + (0<<16), O);
        else
            sweep_run<1,0>(l, sr, 255 - sc0, PRm, costP + (0<<16), costP + (1<<16), costP + (2<<16), O);
        return;
    }

    // ============== HEURISTIC HALF-BLOCK (channels half*64 .. +63) =========
    __shared__ float  stage[CHUNK * SP];
    __shared__ float4 w1L[64 * 8];
    __shared__ float  endfL[64];

    const int t    = threadIdx.x;
    const int hb   = blockIdx.x - 4;
    const int tile = hb & 255;
    const int half = hb >> 8;
    const int r0   = (tile >> 4) * TILE;
    const int c0   = (tile & 15) * TILE;
    const int chB  = half << 6;

    for (int i = t; i < 64 * 8; i += 256) w1L[i] = ((const float4*)w1)[(half << 9) + i];
    const int er = endn[0], ec = endn[1];
    if (half == 0 && t < 64) endfL[t] = feat[(er * Wd + ec) * Cd + t];

    const int lr = t >> 4, lc = t & 15;
    const int r = r0 + lr, c = c0 + lc;
    const int px0 = (lr + 1) * HPX + (lc + 1);

    float4 hv[8];
#pragma unroll
    for (int j = 0; j < 8; ++j) hv[j] = make_float4(0.f, 0.f, 0.f, 0.f);
    float gm_acc = 0.0f, va_acc = 0.0f;

    for (int cc = 0; cc < 2; ++cc) {
        const int ch0 = chB + (cc << 5);
        __syncthreads();
        for (int i = t; i < PXN * 8; i += 256) {
            int pxi = i >> 3, f4 = i & 7;
            int pr = pxi / HPX;
            int pc = pxi - pr * HPX;
            int gr = r0 - 1 + pr, gc = c0 - 1 + pc;
            float4 v = make_float4(0.f, 0.f, 0.f, 0.f);
            if ((unsigned)gr < Hd && (unsigned)gc < Wd) {
                v = *reinterpret_cast<const float4*>(
                        &feat[(((gr << 8) + gc) * Cd) + ch0 + (f4 << 2)]);
            }
            int chb = f4 << 2;
            stage[(chb + 0) * SP + pxi] = v.x;
            stage[(chb + 1) * SP + pxi] = v.y;
            stage[(chb + 2) * SP + pxi] = v.z;
            stage[(chb + 3) * SP + pxi] = v.w;
        }
        __syncthreads();
        for (int ch = 0; ch < CHUNK; ++ch) {
            const float* pl = stage + ch * SP + px0;
            float x  = pl[0];
            float n0 = pl[-HPX - 1], n1 = pl[-HPX], n2 = pl[-HPX + 1];
            float n3 = pl[-1],                      n4 = pl[1];
            float n5 = pl[HPX - 1],  n6 = pl[HPX],  n7 = pl[HPX + 1];

            float gx = (n2 + 2.f * n4 + n7) - (n0 + 2.f * n3 + n5);
            float gy = (n5 + 2.f * n6 + n7) - (n0 + 2.f * n1 + n2);
            gm_acc += sqrtf(gx * gx + gy * gy);

            if (half) {
                float s1 = x + n0 + n1 + n2 + n3 + n4 + n5 + n6 + n7;
                float s2 = x*x + n0*n0 + n1*n1 + n2*n2 + n3*n3 + n4*n4
                         + n5*n5 + n6*n6 + n7*n7;
                float m = s1 * (1.0f / 9.0f);
                va_acc += s2 * (1.0f / 9.0f) - m * m;
            } else {
                float dlf = x - endfL[(cc << 5) + ch];
                va_acc = fmaf(dlf, dlf, va_acc);
            }

            const float4* __restrict__ wr4 = &w1L[((cc << 5) + ch) << 3];
#pragma unroll
            for (int j4 = 0; j4 < 8; ++j4) {
                float4 wv = wr4[j4];
                hv[j4].x = fmaf(x, wv.x, hv[j4].x);
                hv[j4].y = fmaf(x, wv.y, hv[j4].y);
                hv[j4].z = fmaf(x, wv.z, hv[j4].z);
                hv[j4].w = fmaf(x, wv.w, hv[j4].w);
            }
        }
    }

    const int p = (r << 8) + c;
    float* __restrict__ pb = part + (size_t)(half * 34) * PLN;
    pb[p]         = gm_acc;
    pb[PLN + p]   = va_acc;
#pragma unroll
    for (int j4 = 0; j4 < 8; ++j4) {
        pb[(2 + (j4 << 2) + 0) * PLN + p] = hv[j4].x;
        pb[(2 + (j4 << 2) + 1) * PLN + p] = hv[j4].y;
        pb[(2 + (j4 << 2) + 2) * PLN + p] = hv[j4].z;
        pb[(2 + (j4 << 2) + 3) * PLN + p] = hv[j4].w;
    }
}

// ---------------------------------------------------------------------------
// Kernel 4 (R9 byte-exact): merge dist planes + heuristic epilogue (nsh=2).
// ---------------------------------------------------------------------------
__global__ __launch_bounds__(256) void k_merge(
    const float* __restrict__ feat,
    const float* __restrict__ b1, const float* __restrict__ w2,
    const float* __restrict__ b2, const float* __restrict__ dlt,
    const float* __restrict__ gmm, const float* __restrict__ bta,
    const int* __restrict__ endn,
    const float* __restrict__ distQ, const float* __restrict__ part,
    float* __restrict__ out)
{
    __shared__ float vendL[64];
    __shared__ float vendS_;

    const int t = threadIdx.x;
    const int p = blockIdx.x * 256 + t;

    const int er = endn[0], ec = endn[1];
    if (t < 64) {
        float s1 = 0.0f, s2 = 0.0f;
#pragma unroll
        for (int dr = -1; dr <= 1; ++dr)
#pragma unroll
            for (int dc = -1; dc <= 1; ++dc) {
                int gr = er + dr, gc = ec + dc;
                if ((unsigned)gr < Hd && (unsigned)gc < Wd) {
                    float x = feat[((gr << 8) + gc) * Cd + 64 + t];
                    s1 += x; s2 = fmaf(x, x, s2);
                }
            }
        float m = s1 * (1.0f / 9.0f);
        vendL[t] = s2 * (1.0f / 9.0f) - m * m;
    }
    __syncthreads();
    if (t < 64) {
        float v = vendL[t];
#pragma unroll
        for (int o = 32; o > 0; o >>= 1) v += __shfl_down(v, o, 64);
        if (t == 0) vendS_ = v;
    }
    __syncthreads();
    const float vend = vendS_;

    const float* __restrict__ p0 = part;
    const float* __restrict__ p1 = part + (size_t)34 * PLN;
    float gm   = p0[p] + p1[p];
    float abs2 = p0[PLN + p];
    float var  = p1[PLN + p];
    float o = b2[0];
#pragma unroll
    for (int j = 0; j < 32; ++j) {
        float hj = p0[(2 + j) * PLN + p] + p1[(2 + j) * PLN + p] + b1[j];
        o = fmaf(fmaxf(hj, 0.0f), w2[j], o);
    }
    float omg = 1.0f / (1.0f + expf(-o));
    float dS = softplus_f(dlt[0]);
    float gS = softplus_f(gmm[0]);
    float bS = softplus_f(bta[0]);
    float heur = dS * (gm * (1.0f / 128.0f)) + omg * gS * (vend - var)
               + (1.0f - omg) * bS * sqrtf(abs2);
    out[p * 10] = fmaxf(heur, 0.0f);

    int pm = (p & ~255) + (255 - (p & 255));
    float v = fminf(fminf(distQ[p],              distQ[(2 << 16) + p]),
                    fminf(distQ[(1 << 16) + pm], distQ[(3 << 16) + pm]));
    out[p * 10 + 9] = fminf(v, BIGV);
}

// ---------------------------------------------------------------------------
extern "C" void kernel_launch(void* const* d_in, const int* in_sizes, int n_in,
                              void* d_out, int out_size, void* d_ws, size_t ws_size,
                              hipStream_t stream)
{
    const float* feat  = (const float*)d_in[0];
    const float* dlt   = (const float*)d_in[1];
    const float* gmm   = (const float*)d_in[2];
    const float* bta   = (const float*)d_in[3];
    const float* w1    = (const float*)d_in[4];
    const float* b1    = (const float*)d_in[5];
    const float* w2    = (const float*)d_in[6];
    const float* b2    = (const float*)d_in[7];
    const int*   startn= (const int*)d_in[8];
    const int*   endn  = (const int*)d_in[9];
    float* out = (float*)d_out;
    float* ws  = (float*)d_ws;

    float* costP = ws;                    // 8 planes
    float* PR    = ws + 8  * PLN;
    float* PRm   = ws + 9  * PLN;
    float* distQ = ws + 10 * PLN;         // 4 planes
    float* part  = ws + 14 * PLN;         // 68 heuristic-partial planes
    float* pcost = part;                  // 36 cost-partial planes (ALIASED:
                                          // consumed by k_scan before k_main
                                          // overwrites them with heur parts)

    k_costp<<<1024, 256, 0, stream>>>(feat, pcost);
    k_scan<<<256, 256, 0, stream>>>(pcost, costP, PR, PRm, out);
    k_main<<<516, 256, 0, stream>>>(feat, w1, endn,
                                    costP, PR, PRm, startn, distQ, part);
    k_merge<<<256, 256, 0, stream>>>(feat, b1, w2, b2, dlt, gmm, bta, endn,
                                     distQ, part, out);
}

// Round 13
// 161.802 us; speedup vs baseline: 1.2611x; 1.0113x over previous
//
#include <hip/hip_runtime.h>
#include <math.h>

#define Hd 256
#define Wd 256
#define Cd 128
#define BIGV 1.0e9f
#define PLN 65536

typedef float f32x4 __attribute__((ext_vector_type(4)));

static __device__ __forceinline__ float softplus_f(float x) {
    return fmaxf(x, 0.0f) + log1pf(expf(-fabsf(x)));
}

// ---- DPP helpers ----
#define FMAXBITS 0x7F7FFFFF
template<int CTRL, int RM>
static __device__ __forceinline__ float dpp_mv(float x) {
    return __int_as_float(__builtin_amdgcn_update_dpp(
        FMAXBITS, __float_as_int(x), CTRL, RM, 0xF, false));
}
template<int CTRL, int RM>
static __device__ __forceinline__ float dpp_min(float x) {
    return fminf(x, dpp_mv<CTRL, RM>(x));
}
static __device__ __forceinline__ float wave_prefmin(float x) {
    x = dpp_min<0x111, 0xF>(x);
    x = dpp_min<0x112, 0xF>(x);
    x = dpp_min<0x114, 0xF>(x);
    x = dpp_min<0x118, 0xF>(x);
    x = dpp_min<0x142, 0xA>(x);
    x = dpp_min<0x143, 0xC>(x);
    return x;
}

#define TILE 16
#define HPX 18
#define PXN 324
#define SP  325
#define CHUNK 32
#define CHF 16

// ---------------------------------------------------------------------------
// Kernel 1 (R11/R12-proven): cost partials at NS=4. 1024 blocks (tile, 32-ch
// grp), 16-ch staged chunks (LDS 20.8KB -> high occupancy). Writes 9 partial
// planes per group (norm + 8 dots).
// ---------------------------------------------------------------------------
__global__ __launch_bounds__(256) void k_costp(
    const float* __restrict__ feat, float* __restrict__ pcost)
{
    __shared__ float stage[CHF * SP];

    const int t    = threadIdx.x;
    const int tile = blockIdx.x & 255;
    const int grp  = blockIdx.x >> 8;
    const int chB  = grp << 5;
    const int r0   = (tile >> 4) * TILE;
    const int c0   = (tile & 15) * TILE;

    const int lr = t >> 4, lc = t & 15;
    const int r = r0 + lr, c = c0 + lc;
    const int px0 = (lr + 1) * HPX + (lc + 1);

    float dotv[8];
#pragma unroll
    for (int j = 0; j < 8; ++j) dotv[j] = 0.0f;
    float nrm_acc = 0.0f;

    for (int cc = 0; cc < 2; ++cc) {
        const int ch0 = chB + (cc << 4);
        __syncthreads();
        for (int i = t; i < PXN * 4; i += 256) {
            int pxi = i >> 2, f4 = i & 3;
            int pr = pxi / HPX;
            int pc = pxi - pr * HPX;
            int gr = r0 - 1 + pr, gc = c0 - 1 + pc;
            float4 v = make_float4(0.f, 0.f, 0.f, 0.f);
            if ((unsigned)gr < Hd && (unsigned)gc < Wd) {
                v = *reinterpret_cast<const float4*>(
                        &feat[(((gr << 8) + gc) * Cd) + ch0 + (f4 << 2)]);
            }
            int chb = f4 << 2;
            stage[(chb + 0) * SP + pxi] = v.x;
            stage[(chb + 1) * SP + pxi] = v.y;
            stage[(chb + 2) * SP + pxi] = v.z;
            stage[(chb + 3) * SP + pxi] = v.w;
        }
        __syncthreads();
        for (int ch = 0; ch < CHF; ++ch) {
            const float* pl = stage + ch * SP + px0;
            float x  = pl[0];
            float n0 = pl[-HPX - 1], n1 = pl[-HPX], n2 = pl[-HPX + 1];
            float n3 = pl[-1],                      n4 = pl[1];
            float n5 = pl[HPX - 1],  n6 = pl[HPX],  n7 = pl[HPX + 1];
            nrm_acc = fmaf(x, x, nrm_acc);
            dotv[0] = fmaf(x, n0, dotv[0]);
            dotv[1] = fmaf(x, n1, dotv[1]);
            dotv[2] = fmaf(x, n2, dotv[2]);
            dotv[3] = fmaf(x, n3, dotv[3]);
            dotv[4] = fmaf(x, n4, dotv[4]);
            dotv[5] = fmaf(x, n5, dotv[5]);
            dotv[6] = fmaf(x, n6, dotv[6]);
            dotv[7] = fmaf(x, n7, dotv[7]);
        }
    }

    const int p = (r << 8) + c;
    float* __restrict__ pb = pcost + (size_t)grp * 9 * PLN;
    pb[p] = nrm_acc;
#pragma unroll
    for (int j = 0; j < 8; ++j) pb[(1 + j) * PLN + p] = dotv[j];
}

// ---------------------------------------------------------------------------
// Kernel 2 (R11/R12-proven): cost FINISH (4-group sums) + per-row scans.
// ---------------------------------------------------------------------------
__global__ __launch_bounds__(256) void k_scan(
    const float* __restrict__ pcost, float* __restrict__ costP,
    float* __restrict__ PR, float* __restrict__ PRm,
    float* __restrict__ out)
{
    __shared__ float nrm[3 * 256];
    __shared__ float cE[256], cW[256];

    const int t = threadIdx.x;
    const int r = blockIdx.x;

    for (int i = t; i < 3 * 256; i += 256) {
        int rr = r - 1 + (i >> 8);
        int pc = i & 255;
        float s = 0.0f;
        if ((unsigned)rr < Hd)
#pragma unroll
            for (int g = 0; g < 4; ++g)
                s += pcost[(size_t)g * 9 * PLN + (rr << 8) + pc];
        nrm[i] = fmaxf(sqrtf(s), 1e-12f);
    }
    __syncthreads();

    const int p = (r << 8) + t;
    const float npv = nrm[256 + t];
    const int drr[8] = {-1,-1,-1, 0, 0, 1, 1, 1};
    const int dcc[8] = {-1, 0, 1,-1, 1,-1, 0, 1};
#pragma unroll
    for (int j = 0; j < 8; ++j) {
        int nr = r + drr[j], nc = t + dcc[j];
        float cj;
        if ((unsigned)nr < Hd && (unsigned)nc < Wd) {
            float dot = 0.0f;
#pragma unroll
            for (int g = 0; g < 4; ++g)
                dot += pcost[(size_t)g * 9 * PLN + (1 + j) * PLN + p];
            float nn = nrm[((drr[j] + 1) << 8) + nc];
            cj = 1.0f - dot / (npv * nn);
        } else {
            cj = BIGV;
        }
        costP[(j << 16) + p] = cj;
        out[p * 10 + 1 + j]  = cj;
        if (j == 4) cE[t] = cj;
        if (j == 3) cW[t] = cj;
    }
    __syncthreads();

    if (t < 64) {
        const int l = t;
        const int base = (r << 8) + (l << 2);
        {
            float a0 = cE[(l << 2) + 0];
            float a1 = a0 + cE[(l << 2) + 1];
            float a2 = a1 + cE[(l << 2) + 2];
            float a3 = a2 + cE[(l << 2) + 3];
            float ta = a3;
#pragma unroll
            for (int o = 1; o < 64; o <<= 1) {
                float xa = __shfl_up(ta, o, 64);
                if (l >= o) ta += xa;
            }
            float ea = __shfl_up(ta, 1, 64); if (l == 0) ea = 0.0f;
            float4 P; P.x = ea; P.y = ea + a0; P.z = ea + a1; P.w = ea + a2;
            *(float4*)&PR[base] = P;
        }
        {
            float w0 = cW[255 - (l << 2)];
            float w1_ = cW[254 - (l << 2)];
            float w2_ = cW[253 - (l << 2)];
            float w3 = cW[252 - (l << 2)];
            float a0 = w0, a1 = a0 + w1_, a2 = a1 + w2_, a3 = a2 + w3;
            float ta = a3;
#pragma unroll
            for (int o = 1; o < 64; o <<= 1) {
                float xa = __shfl_up(ta, o, 64);
                if (l >= o) ta += xa;
            }
            float ea = __shfl_up(ta, 1, 64); if (l == 0) ea = 0.0f;
            float4 P; P.x = ea; P.y = ea + a0; P.z = ea + a1; P.w = ea + a2;
            *(float4*)&PRm[base] = P;
        }
    }
}

// ---------------------------------------------------------------------------
// R5-EXACT sweep core (proven 47.5us standalone): volatile-asm pipelined,
// SDEPTH=4. R6: deeper register pipelines spill. R11: LDS-staged rebuild
// loses. This register core is the best known -- keep.
// ---------------------------------------------------------------------------
#define SDEPTH 4

template<int VD> static __device__ __forceinline__ int row_of(int ii) {
    int c = ii > 255 ? 255 : ii;
    return VD ? c : 255 - c;
}
template<int VD> static __device__ __forceinline__ int rowp_of(int ii) {
    int c = ii - 1; c = c < 0 ? 0 : (c > 255 ? 255 : c);
    return VD ? c : 255 - c;
}

template<int M, int VD>
static __device__ __forceinline__ void sweep_run(
    int l, int sr, int sc,
    const float* __restrict__ PRu,
    const float* __restrict__ cInP,
    const float* __restrict__ cStP,
    const float* __restrict__ cDeP,
    float* __restrict__ O)
{
    const int lane4 = l << 2;
    f32x4 sv = {BIGV, BIGV, BIGV, BIGV};
    {
        int kk = sc - lane4;
        if (kk == 0) sv[0] = 0.0f;
        if (kk == 1) sv[1] = 0.0f;
        if (kk == 2) sv[2] = 0.0f;
        if (kk == 3) sv[3] = 0.0f;
    }
    const int iStart = VD ? sr : 255 - sr;

    f32x4 bPR[SDEPTH], bI[SDEPTH], bS[SDEPTH], bD[SDEPTH];
    f32x4 Dp = {BIGV, BIGV, BIGV, BIGV};

#define KXc(v) (M ? (v)[3] : (v)[0])
#define KYc(v) (M ? (v)[2] : (v)[1])
#define KZc(v) (M ? (v)[1] : (v)[2])
#define KWc(v) (M ? (v)[0] : (v)[3])

#define SW_ISSUE(slot, jn) do {                                               \
        int rP_ = row_of<VD>(jn), rC_ = rowp_of<VD>(jn);                      \
        int voffP_ = ((rP_ << 8) + lane4) << 2;                               \
        int voffC_ = (M ? ((rC_ << 8) + 252 - lane4)                          \
                        : ((rC_ << 8) + lane4)) << 2;                         \
        asm volatile("global_load_dwordx4 %0, %1, %2"                         \
                     : "=v"(bPR[slot]) : "v"(voffP_), "s"(PRu));              \
        asm volatile("global_load_dwordx4 %0, %1, %2"                         \
                     : "=v"(bI[slot])  : "v"(voffC_), "s"(cInP));             \
        asm volatile("global_load_dwordx4 %0, %1, %2"                         \
                     : "=v"(bS[slot])  : "v"(voffC_), "s"(cStP));             \
        asm volatile("global_load_dwordx4 %0, %1, %2"                         \
                     : "=v"(bD[slot])  : "v"(voffC_), "s"(cDeP));             \
    } while (0)

#define SW_WAIT(n) do {                                                       \
        asm volatile("s_waitcnt vmcnt(" #n ")");                              \
        __builtin_amdgcn_sched_barrier(0);                                    \
    } while (0)

#define SW_BODY(slot, ivar) do {                                              \
        const int i__ = (ivar);                                               \
        const int r__ = VD ? i__ : 255 - i__;                                 \
        f32x4 PRc = bPR[slot];                                                \
        float tS0 = Dp[0] + KXc(bS[slot]), tS1 = Dp[1] + KYc(bS[slot]);       \
        float tS2 = Dp[2] + KZc(bS[slot]), tS3 = Dp[3] + KWc(bS[slot]);       \
        float tI0 = Dp[0] + KXc(bI[slot]), tI1 = Dp[1] + KYc(bI[slot]);       \
        float tI2 = Dp[2] + KZc(bI[slot]), tI3 = Dp[3] + KWc(bI[slot]);       \
        float tD0 = Dp[0] + KXc(bD[slot]), tD1 = Dp[1] + KYc(bD[slot]);       \
        float tD2 = Dp[2] + KZc(bD[slot]), tD3 = Dp[3] + KWc(bD[slot]);       \
        float tIm = dpp_mv<0x138, 0xF>(tI3);   /* wave_shr1 */                \
        float tDn = dpp_mv<0x130, 0xF>(tD0);   /* wave_shl1 */                \
        f32x4 cand;                                                           \
        cand[0] = fminf(tS0, fminf(tIm, tD1));                                \
        cand[1] = fminf(tS1, fminf(tI0, tD2));                                \
        cand[2] = fminf(tS2, fminf(tI1, tD3));                                \
        cand[3] = fminf(tS3, fminf(tI2, tDn));                                \
        if (i__ == iStart) {                                                  \
            cand[0] = fminf(cand[0], sv[0]); cand[1] = fminf(cand[1], sv[1]); \
            cand[2] = fminf(cand[2], sv[2]); cand[3] = fminf(cand[3], sv[3]); \
        }                                                                     \
        float z0 = cand[0] - PRc[0];                                          \
        float z1 = fminf(cand[1] - PRc[1], z0);                               \
        float z2 = fminf(cand[2] - PRc[2], z1);                               \
        float z3 = fminf(cand[3] - PRc[3], z2);                               \
        float w__ = wave_prefmin(z3);                                         \
        float e__ = dpp_mv<0x138, 0xF>(w__);   /* exclusive prefix */         \
        f32x4 D__;                                                            \
        D__[0] = PRc[0] + fminf(z0, e__);                                     \
        D__[1] = PRc[1] + fminf(z1, e__);                                     \
        D__[2] = PRc[2] + fminf(z2, e__);                                     \
        D__[3] = PRc[3] + fminf(z3, e__);                                     \
        int voffO_ = ((r__ << 8) + lane4) << 2;                               \
        asm volatile("global_store_dwordx4 %0, %1, %2"                        \
                     :: "v"(voffO_), "v"(D__), "s"(O));                       \
        Dp = D__;                                                             \
        SW_ISSUE(slot, i__ + SDEPTH);                                         \
    } while (0)

#pragma unroll
    for (int k = 0; k < SDEPTH; ++k) SW_ISSUE(k, k);

    SW_WAIT(12); SW_BODY(0, 0);
    SW_WAIT(13); SW_BODY(1, 1);
    SW_WAIT(14); SW_BODY(2, 2);
    SW_WAIT(15); SW_BODY(3, 3);
    for (int ib = SDEPTH; ib < 256; ib += SDEPTH) {
        SW_WAIT(15); SW_BODY(0, ib + 0);
        SW_WAIT(15); SW_BODY(1, ib + 1);
        SW_WAIT(15); SW_BODY(2, ib + 2);
        SW_WAIT(15); SW_BODY(3, ib + 3);
    }
    asm volatile("s_waitcnt vmcnt(0)");

#undef SW_ISSUE
#undef SW_WAIT
#undef SW_BODY
#undef KXc
#undef KYc
#undef KZc
#undef KWc
}

// ---------------------------------------------------------------------------
// Kernel 3 (R9 byte-exact): blocks 0..3 = sweeps; 4..515 = heuristic
// half-blocks (64ch, 49KB LDS -> 3 blocks/CU).
// ---------------------------------------------------------------------------
__global__ __launch_bounds__(256) void k_main(
    const float* __restrict__ feat,
    const float* __restrict__ w1,
    const int* __restrict__ endn,
    const float* __restrict__ costP, const float* __restrict__ PR,
    const float* __restrict__ PRm, const int* __restrict__ startn,
    float* __restrict__ distQ, float* __restrict__ part)
{
    if (blockIdx.x < 4) {
        const int l = threadIdx.x;
        if (l >= 64) return;
        __builtin_amdgcn_s_setprio(1);
        const int sw  = blockIdx.x;
        const int sr  = startn[0];
        const int sc0 = startn[1];
        float* O = distQ + (sw << 16);
        if (sw == 0)
            sweep_run<0,1>(l, sr, sc0,       PR,  costP + (7<<16), costP + (6<<16), costP + (5<<16), O);
        else if (sw == 1)
            sweep_run<1,1>(l, sr, 255 - sc0, PRm, costP + (5<<16), costP + (6<<16), costP + (7<<16), O);
        else if (sw == 2)
            sweep_run<0,0>(l, sr, sc0,       PR,  costP + (2<<16), costP + (1<<16), costP + (0<<16), O);
        else
            sweep_run<1,0>(l, sr, 255 - sc0, PRm, costP + (0<<16), costP + (1<<16), costP + (2<<16), O);
        return;
    }

    // ============== HEURISTIC HALF-BLOCK (channels half*64 .. +63) =========
    __shared__ float  stage[CHUNK * SP];
    __shared__ float4 w1L[64 * 8];
    __shared__ float  endfL[64];

    const int t    = threadIdx.x;
    const int hb   = blockIdx.x - 4;
    const int tile = hb & 255;
    const int half = hb >> 8;
    const int r0   = (tile >> 4) * TILE;
    const int c0   = (tile & 15) * TILE;
    const int chB  = half << 6;

    for (int i = t; i < 64 * 8; i += 256) w1L[i] = ((const float4*)w1)[(half << 9) + i];
    const int er = endn[0], ec = endn[1];
    if (half == 0 && t < 64) endfL[t] = feat[(er * Wd + ec) * Cd + t];

    const int lr = t >> 4, lc = t & 15;
    const int r = r0 + lr, c = c0 + lc;
    const int px0 = (lr + 1) * HPX + (lc + 1);

    float4 hv[8];
#pragma unroll
    for (int j = 0; j < 8; ++j) hv[j] = make_float4(0.f, 0.f, 0.f, 0.f);
    float gm_acc = 0.0f, va_acc = 0.0f;

    for (int cc = 0; cc < 2; ++cc) {
        const int ch0 = chB + (cc << 5);
        __syncthreads();
        for (int i = t; i < PXN * 8; i += 256) {
            int pxi = i >> 3, f4 = i & 7;
            int pr = pxi / HPX;
            int pc = pxi - pr * HPX;
            int gr = r0 - 1 + pr, gc = c0 - 1 + pc;
            float4 v = make_float4(0.f, 0.f, 0.f, 0.f);
            if ((unsigned)gr < Hd && (unsigned)gc < Wd) {
                v = *reinterpret_cast<const float4*>(
                        &feat[(((gr << 8) + gc) * Cd) + ch0 + (f4 << 2)]);
            }
            int chb = f4 << 2;
            stage[(chb + 0) * SP + pxi] = v.x;
            stage[(chb + 1) * SP + pxi] = v.y;
            stage[(chb + 2) * SP + pxi] = v.z;
            stage[(chb + 3) * SP + pxi] = v.w;
        }
        __syncthreads();
        for (int ch = 0; ch < CHUNK; ++ch) {
            const float* pl = stage + ch * SP + px0;
            float x  = pl[0];
            float n0 = pl[-HPX - 1], n1 = pl[-HPX], n2 = pl[-HPX + 1];
            float n3 = pl[-1],                      n4 = pl[1];
            float n5 = pl[HPX - 1],  n6 = pl[HPX],  n7 = pl[HPX + 1];

            float gx = (n2 + 2.f * n4 + n7) - (n0 + 2.f * n3 + n5);
            float gy = (n5 + 2.f * n6 + n7) - (n0 + 2.f * n1 + n2);
            gm_acc += sqrtf(gx * gx + gy * gy);

            if (half) {
                float s1 = x + n0 + n1 + n2 + n3 + n4 + n5 + n6 + n7;
                float s2 = x*x + n0*n0 + n1*n1 + n2*n2 + n3*n3 + n4*n4
                         + n5*n5 + n6*n6 + n7*n7;
                float m = s1 * (1.0f / 9.0f);
                va_acc += s2 * (1.0f / 9.0f) - m * m;
            } else {
                float dlf = x - endfL[(cc << 5) + ch];
                va_acc = fmaf(dlf, dlf, va_acc);
            }

            const float4* __restrict__ wr4 = &w1L[((cc << 5) + ch) << 3];
#pragma unroll
            for (int j4 = 0; j4 < 8; ++j4) {
                float4 wv = wr4[j4];
                hv[j4].x = fmaf(x, wv.x, hv[j4].x);
                hv[j4].y = fmaf(x, wv.y, hv[j4].y);
                hv[j4].z = fmaf(x, wv.z, hv[j4].z);
                hv[j4].w = fmaf(x, wv.w, hv[j4].w);
            }
        }
    }

    const int p = (r << 8) + c;
    float* __restrict__ pb = part + (size_t)(half * 34) * PLN;
    pb[p]         = gm_acc;
    pb[PLN + p]   = va_acc;
#pragma unroll
    for (int j4 = 0; j4 < 8; ++j4) {
        pb[(2 + (j4 << 2) + 0) * PLN + p] = hv[j4].x;
        pb[(2 + (j4 << 2) + 1) * PLN + p] = hv[j4].y;
        pb[(2 + (j4 << 2) + 2) * PLN + p] = hv[j4].z;
        pb[(2 + (j4 << 2) + 3) * PLN + p] = hv[j4].w;
    }
}

// ---------------------------------------------------------------------------
// Kernel 4 (R9 byte-exact): merge dist planes + heuristic epilogue (nsh=2).
// ---------------------------------------------------------------------------
__global__ __launch_bounds__(256) void k_merge(
    const float* __restrict__ feat,
    const float* __restrict__ b1, const float* __restrict__ w2,
    const float* __restrict__ b2, const float* __restrict__ dlt,
    const float* __restrict__ gmm, const float* __restrict__ bta,
    const int* __restrict__ endn,
    const float* __restrict__ distQ, const float* __restrict__ part,
    float* __restrict__ out)
{
    __shared__ float vendL[64];
    __shared__ float vendS_;

    const int t = threadIdx.x;
    const int p = blockIdx.x * 256 + t;

    const int er = endn[0], ec = endn[1];
    if (t < 64) {
        float s1 = 0.0f, s2 = 0.0f;
#pragma unroll
        for (int dr = -1; dr <= 1; ++dr)
#pragma unroll
            for (int dc = -1; dc <= 1; ++dc) {
                int gr = er + dr, gc = ec + dc;
                if ((unsigned)gr < Hd && (unsigned)gc < Wd) {
                    float x = feat[((gr << 8) + gc) * Cd + 64 + t];
                    s1 += x; s2 = fmaf(x, x, s2);
                }
            }
        float m = s1 * (1.0f / 9.0f);
        vendL[t] = s2 * (1.0f / 9.0f) - m * m;
    }
    __syncthreads();
    if (t < 64) {
        float v = vendL[t];
#pragma unroll
        for (int o = 32; o > 0; o >>= 1) v += __shfl_down(v, o, 64);
        if (t == 0) vendS_ = v;
    }
    __syncthreads();
    const float vend = vendS_;

    const float* __restrict__ p0 = part;
    const float* __restrict__ p1 = part + (size_t)34 * PLN;
    float gm   = p0[p] + p1[p];
    float abs2 = p0[PLN + p];
    float var  = p1[PLN + p];
    float o = b2[0];
#pragma unroll
    for (int j = 0; j < 32; ++j) {
        float hj = p0[(2 + j) * PLN + p] + p1[(2 + j) * PLN + p] + b1[j];
        o = fmaf(fmaxf(hj, 0.0f), w2[j], o);
    }
    float omg = 1.0f / (1.0f + expf(-o));
    float dS = softplus_f(dlt[0]);
    float gS = softplus_f(gmm[0]);
    float bS = softplus_f(bta[0]);
    float heur = dS * (gm * (1.0f / 128.0f)) + omg * gS * (vend - var)
               + (1.0f - omg) * bS * sqrtf(abs2);
    out[p * 10] = fmaxf(heur, 0.0f);

    int pm = (p & ~255) + (255 - (p & 255));
    float v = fminf(fminf(distQ[p],              distQ[(2 << 16) + p]),
                    fminf(distQ[(1 << 16) + pm], distQ[(3 << 16) + pm]));
    out[p * 10 + 9] = fminf(v, BIGV);
}

// ---------------------------------------------------------------------------
extern "C" void kernel_launch(void* const* d_in, const int* in_sizes, int n_in,
                              void* d_out, int out_size, void* d_ws, size_t ws_size,
                              hipStream_t stream)
{
    const float* feat  = (const float*)d_in[0];
    const float* dlt   = (const float*)d_in[1];
    const float* gmm   = (const float*)d_in[2];
    const float* bta   = (const float*)d_in[3];
    const float* w1    = (const float*)d_in[4];
    const float* b1    = (const float*)d_in[5];
    const float* w2    = (const float*)d_in[6];
    const float* b2    = (const float*)d_in[7];
    const int*   startn= (const int*)d_in[8];
    const int*   endn  = (const int*)d_in[9];
    float* out = (float*)d_out;
    float* ws  = (float*)d_ws;

    float* costP = ws;                    // 8 planes
    float* PR    = ws + 8  * PLN;
    float* PRm   = ws + 9  * PLN;
    float* distQ = ws + 10 * PLN;         // 4 planes
    float* part  = ws + 14 * PLN;         // 68 heuristic-partial planes

    // R13: UN-ALIAS pcost from part. The aliased layout made k_main's
    // partial stores hit lines dirty in other XCDs' L2s (written by 1024
    // k_costp blocks) -> cross-XCD ownership churn, k_main 52 -> 58.7us
    // (R9 -> R12). Separate region removes the collision; fall back to the
    // aliased (R12-proven-correct) layout only if ws can't hold 118 planes.
    const size_t needU = (size_t)(14 + 68 + 36) * PLN * sizeof(float);
    float* pcost = (ws_size >= needU) ? (ws + (size_t)(14 + 68) * PLN) : part;

    k_costp<<<1024, 256, 0, stream>>>(feat, pcost);
    k_scan<<<256, 256, 0, stream>>>(pcost, costP, PR, PRm, out);
    k_main<<<516, 256, 0, stream>>>(feat, w1, endn,
                                    costP, PR, PRm, startn, distQ, part);
    k_merge<<<256, 256, 0, stream>>>(feat, b1, w2, b2, dlt, gmm, bta, endn,
                                     distQ, part, out);
}